// Round 6
// baseline (559.361 us; speedup 1.0000x reference)
//
#include <hip/hip_runtime.h>
#include <cmath>
#include <cstdint>

namespace {

constexpr int kLevels = 12;      // MAX_LEVELS=12 -> levels >= 12 always masked out
constexpr unsigned kNB = 32768;  // 32^3 Morton buckets
constexpr unsigned kTileCap = 512;  // entries (float2) per-wave tile arena

typedef float f32x4 __attribute__((ext_vector_type(4)));
typedef float f32x4u __attribute__((ext_vector_type(4), aligned(8)));

struct LevelMeta { float scale; unsigned res; unsigned size; unsigned off; };
struct Meta { LevelMeta lv[kLevels]; };

__device__ inline unsigned spread5(unsigned v) {
  v &= 31u;
  v = (v | (v << 8)) & 0x0000100Fu;
  v = (v | (v << 4)) & 0x000010C3u;
  v = (v | (v << 2)) & 0x00001249u;
  return v;
}

__device__ inline unsigned bucket_of(float x, float y, float z) {
  unsigned xi = (unsigned)fminf(fmaxf(x * 32.0f, 0.0f), 31.0f);
  unsigned yi = (unsigned)fminf(fmaxf(y * 32.0f, 0.0f), 31.0f);
  unsigned zi = (unsigned)fminf(fmaxf(z * 32.0f, 0.0f), 31.0f);
  return spread5(xi) | (spread5(yi) << 1) | (spread5(zi) << 2);
}

}  // namespace

// ---------------- sort prefix ----------------

__global__ __launch_bounds__(256) void k_hist(const float* __restrict__ xyz,
                                              unsigned* __restrict__ counts, int n) {
  const int i = blockIdx.x * blockDim.x + threadIdx.x;
  if (i >= n) return;
  atomicAdd(&counts[bucket_of(xyz[3 * i], xyz[3 * i + 1], xyz[3 * i + 2])], 1u);
}

__global__ __launch_bounds__(1024) void k_scan(const unsigned* __restrict__ counts,
                                               unsigned* __restrict__ cursor) {
  __shared__ unsigned part[1024];
  const int t = threadIdx.x;
  const int base = t * 32;
  unsigned loc[32];
  unsigned run = 0;
#pragma unroll
  for (int j = 0; j < 32; ++j) { loc[j] = run; run += counts[base + j]; }
  part[t] = run;
  __syncthreads();
  for (int off = 1; off < 1024; off <<= 1) {
    unsigned v = (t >= off) ? part[t - off] : 0u;
    __syncthreads();
    part[t] += v;
    __syncthreads();
  }
  const unsigned ebase = part[t] - run;
#pragma unroll
  for (int j = 0; j < 32; ++j) cursor[base + j] = ebase + loc[j];
}

__global__ __launch_bounds__(256) void k_scatter(const float* __restrict__ xyz,
                                                 unsigned* __restrict__ cursor,
                                                 f32x4* __restrict__ sorted, int n) {
  const int i = blockIdx.x * blockDim.x + threadIdx.x;
  if (i >= n) return;
  const float x = xyz[3 * i], y = xyz[3 * i + 1], z = xyz[3 * i + 2];
  const unsigned pos = atomicAdd(&cursor[bucket_of(x, y, z)], 1u);
  f32x4 v;
  v.x = x; v.y = y; v.z = z; v.w = __uint_as_float((unsigned)i);
  sorted[pos] = v;
}

// ---------------- main: wave-cooperative LDS tiles over sorted points ----------------

__global__ __launch_bounds__(256) void k_main_sorted(
    const f32x4* __restrict__ sorted,
    const float* __restrict__ txy,
    const float* __restrict__ tyz,
    const float* __restrict__ txz,
    const int* __restrict__ step_ptr,
    float* __restrict__ out,
    int n, Meta meta)
{
  // staging: [4 waves][8 chunks][260 floats]; tiles: [4 waves][512 float2]; idxs
  __shared__ float stg[4 * 2080];
  __shared__ float2 tiles[4 * kTileCap];
  __shared__ unsigned idxs[256];

  const int tid = threadIdx.x;
  const int wid = tid >> 6;
  const int lane = tid & 63;
  const int g = blockIdx.x * 256 + tid;
  const bool valid = g < n;
  const f32x4 s = sorted[valid ? g : (n - 1)];
  const unsigned row = valid ? __float_as_uint(s.w) : 0xFFFFFFFFu;

  const int step = *step_ptr;
  int level = step / 1000 + 1;
  level = level > kLevels ? kLevels : level;

  // wave bbox of the 3 coords (all 64 lanes valid: tail lanes hold point n-1)
  float mnx = s.x, mxx = s.x, mny = s.y, mxy = s.y, mnz = s.z, mxz = s.z;
#pragma unroll
  for (int m = 1; m < 64; m <<= 1) {
    mnx = fminf(mnx, __shfl_xor(mnx, m)); mxx = fmaxf(mxx, __shfl_xor(mxx, m));
    mny = fminf(mny, __shfl_xor(mny, m)); mxy = fmaxf(mxy, __shfl_xor(mxy, m));
    mnz = fminf(mnz, __shfl_xor(mnz, m)); mxz = fmaxf(mxz, __shfl_xor(mxz, m));
  }

  float2* tile = &tiles[wid * kTileCap];
  float* wlds = stg + wid * 2080;

  // zero feature chunks 6,7 (levels 12..15 always masked)
  {
    const f32x4 z = {0.0f, 0.0f, 0.0f, 0.0f};
    *reinterpret_cast<f32x4*>(wlds + 6 * 260 + lane * 4) = z;
    *reinterpret_cast<f32x4*>(wlds + 7 * 260 + lane * 4) = z;
  }

  // one (level, plane) at a time; tile arena reused sequentially (in-order DS per wave)
  for (int l = 0; l < kLevels; ++l) {
    const LevelMeta lm = meta.lv[l];
    float a0 = 0.0f, a1 = 0.0f;

    auto plane = [&](float c0, float c1, float lo0, float hi0, float lo1, float hi1,
                     const float* __restrict__ tabf) {
      const float2* __restrict__ tab = reinterpret_cast<const float2*>(tabf) + lm.off;

      const float posx = fmaf(c0, lm.scale, 0.5f);
      const float posy = fmaf(c1, lm.scale, 0.5f);
      const float g0x = floorf(posx);
      const float g0y = floorf(posy);
      const float fx = posx - g0x;
      const float fy = posy - g0y;
      const unsigned ix = (unsigned)g0x;
      const unsigned iy = (unsigned)g0y;

      // wave-uniform tile bounds (fmaf/floor monotone in c -> bounds hold per-lane)
      const unsigned ix0 = (unsigned)floorf(fmaf(lo0, lm.scale, 0.5f));
      const unsigned ix1 = (unsigned)floorf(fmaf(hi0, lm.scale, 0.5f));
      const unsigned iy0 = (unsigned)floorf(fmaf(lo1, lm.scale, 0.5f));
      const unsigned iy1 = (unsigned)floorf(fmaf(hi1, lm.scale, 0.5f));
      const unsigned C = ix1 - ix0 + 2u;
      const unsigned R = iy1 - iy0 + 2u;
      const unsigned S = C | 1u;  // odd stride: bank decorrelation

      float2 q00, q01, q10, q11;
      if (C <= 64u && R * S <= kTileCap) {
        // cooperative coalesced tile load, 2-deep pipelined
        const unsigned kk = 32u - __builtin_clz(C - 1u);  // C >= 2 always
        const unsigned rpi = 64u >> kk;
        const unsigned I = (R + rpi - 1u) >> (6u - kk);
        const unsigned rr = lane >> kk;
        const unsigned cc = lane & ((1u << kk) - 1u);

        float2 v0 = make_float2(0.0f, 0.0f);
        unsigned d0 = rr * S + cc;
        bool ok0 = (cc < C) & (rr < R);
        {
          unsigned gi = (iy0 + rr) * lm.res + ix0 + cc;  // per-entry wrap == ref's %
          if (gi >= lm.size) gi -= lm.size;
          if (ok0) v0 = tab[gi];
        }
        for (unsigned t = 1; t < I; ++t) {
          const unsigned r = t * rpi + rr;
          float2 v1 = make_float2(0.0f, 0.0f);
          const bool ok1 = (cc < C) & (r < R);
          unsigned gi = (iy0 + r) * lm.res + ix0 + cc;
          if (gi >= lm.size) gi -= lm.size;
          if (ok1) v1 = tab[gi];
          if (ok0) tile[d0] = v0;
          v0 = v1; d0 = r * S + cc; ok0 = ok1;
        }
        if (ok0) tile[d0] = v0;

        const unsigned a = (iy - iy0) * S + (ix - ix0);
        q00 = tile[a];
        q10 = tile[a + 1];
        q01 = tile[a + S];
        q11 = tile[a + S + 1];
      } else {
        // divergent-gather fallback (rare: Morton jumps / fine-level straddles)
        unsigned i00 = ix + iy * lm.res;            // < size always
        unsigned i01 = i00 + lm.res;                // < 2*size
        if (i01 >= lm.size) i01 -= lm.size;
        const f32x4 r0 = *reinterpret_cast<const f32x4u*>(tab + i00);
        const f32x4 r1 = *reinterpret_cast<const f32x4u*>(tab + i01);
        const float2 tf = *tab;                     // wrap target is entry 0
        const bool w0 = (i00 == lm.size - 1u);
        const bool w1 = (i01 == lm.size - 1u);
        q00 = make_float2(r0.x, r0.y);
        q10 = w0 ? tf : make_float2(r0.z, r0.w);
        q01 = make_float2(r1.x, r1.y);
        q11 = w1 ? tf : make_float2(r1.z, r1.w);
      }

      const float w00 = (1.0f - fx) * (1.0f - fy);
      const float w01 = (1.0f - fx) * fy;
      const float w10 = fx * (1.0f - fy);
      const float w11 = fx * fy;
      a0 += w00 * q00.x + w01 * q01.x + w10 * q10.x + w11 * q11.x;
      a1 += w00 * q00.y + w01 * q01.y + w10 * q10.y + w11 * q11.y;
    };

    plane(s.x, s.y, mnx, mxx, mny, mxy, txy);
    plane(s.y, s.z, mny, mxy, mnz, mxz, tyz);
    plane(s.x, s.z, mnx, mxx, mnz, mxz, txz);

    // stream features (2l, 2l+1) into staging; masked levels write zeros
    float2 pr = (l < level) ? make_float2(a0, a1) : make_float2(0.0f, 0.0f);
    const int chunk = l >> 1;
    const int ofs = (l & 1) * 2;
    *reinterpret_cast<float2*>(wlds + chunk * 260 + lane * 4 + ofs) = pr;
  }

  idxs[tid] = row;
  __syncthreads();

  // write back: each store covers a whole 128B output row chunk (coalesced)
#pragma unroll
  for (int q = 0; q < 8; ++q) {
    const int p = q * 8 + (lane >> 3);   // point within wave
    const int c = lane & 7;              // 16B chunk within row
    const unsigned r = idxs[wid * 64 + p];
    const f32x4 v = *reinterpret_cast<const f32x4*>(wlds + c * 260 + p * 4);
    if (r != 0xFFFFFFFFu)
      __builtin_nontemporal_store(v, reinterpret_cast<f32x4*>(out) + (size_t)r * 8 + c);
  }
}

// ---------------- fallback (no-sort) if ws too small ----------------

__global__ __launch_bounds__(256) void k_fused_linear(
    const float* __restrict__ xyz,
    const float* __restrict__ txy,
    const float* __restrict__ tyz,
    const float* __restrict__ txz,
    const int* __restrict__ step_ptr,
    float* __restrict__ out,
    int n, Meta meta)
{
  __shared__ float lds[4 * 2048];
  const int tid = threadIdx.x;
  const int wid = tid >> 6;
  const int lane = tid & 63;
  const int bbase = blockIdx.x * 256;
  const int i = bbase + tid;
  const int pi = i < n ? i : (n - 1);

  const int step = *step_ptr;
  int level = step / 1000 + 1;
  level = level > kLevels ? kLevels : level;
  const int active = 2 * level;

  const float px = xyz[3 * pi], py = xyz[3 * pi + 1], pz = xyz[3 * pi + 2];
  float acc[2 * kLevels];
#pragma unroll
  for (int k = 0; k < 2 * kLevels; ++k) acc[k] = 0.0f;

  auto do_plane = [&](float c0, float c1, const float* __restrict__ tabf) {
    const float2* __restrict__ tab = reinterpret_cast<const float2*>(tabf);
#pragma unroll
    for (int l = 0; l < kLevels; ++l) {
      const LevelMeta lm = meta.lv[l];
      const float2* tb = tab + lm.off;
      const float posx = fmaf(c0, lm.scale, 0.5f);
      const float posy = fmaf(c1, lm.scale, 0.5f);
      const float g0x = floorf(posx), g0y = floorf(posy);
      const float fx = posx - g0x, fy = posy - g0y;
      const unsigned ix = (unsigned)g0x, iy = (unsigned)g0y;
      unsigned i00 = ix + iy * lm.res;
      unsigned i01 = i00 + lm.res;
      if (i01 >= lm.size) i01 -= lm.size;
      const f32x4 r0 = *reinterpret_cast<const f32x4u*>(tb + i00);
      const f32x4 r1 = *reinterpret_cast<const f32x4u*>(tb + i01);
      const float2 tf = *tb;
      const bool w0 = (i00 == lm.size - 1u), w1 = (i01 == lm.size - 1u);
      const float t10x = w0 ? tf.x : r0.z, t10y = w0 ? tf.y : r0.w;
      const float t11x = w1 ? tf.x : r1.z, t11y = w1 ? tf.y : r1.w;
      const float w00 = (1.0f - fx) * (1.0f - fy);
      const float w01 = (1.0f - fx) * fy;
      const float w10 = fx * (1.0f - fy);
      const float w11 = fx * fy;
      acc[2 * l + 0] += w00 * r0.x + w01 * r1.x + w10 * t10x + w11 * t11x;
      acc[2 * l + 1] += w00 * r0.y + w01 * r1.y + w10 * t10y + w11 * t11y;
    }
  };
  do_plane(px, py, txy);
  do_plane(py, pz, tyz);
  do_plane(px, pz, txz);

#pragma unroll
  for (int k = 0; k < 2 * kLevels; ++k)
    if (k >= active) acc[k] = 0.0f;

  float* wlds = lds + wid * 2048;
#pragma unroll
  for (int c = 0; c < 8; ++c) {
    f32x4 v;
    v.x = c < 6 ? acc[4 * c + 0] : 0.0f;
    v.y = c < 6 ? acc[4 * c + 1] : 0.0f;
    v.z = c < 6 ? acc[4 * c + 2] : 0.0f;
    v.w = c < 6 ? acc[4 * c + 3] : 0.0f;
    *reinterpret_cast<f32x4*>(wlds + c * 256 + lane * 4) = v;
  }
  __syncthreads();

  const long long wbase = (long long)bbase + wid * 64;
  f32x4* obase = reinterpret_cast<f32x4*>(out) + wbase * 8;
#pragma unroll
  for (int q = 0; q < 8; ++q) {
    const int p = q * 8 + (lane >> 3);
    const int c = lane & 7;
    const f32x4 v = *reinterpret_cast<const f32x4*>(wlds + c * 256 + p * 4);
    if (wbase + p < n)
      __builtin_nontemporal_store(v, obase + q * 64 + lane);
  }
}

extern "C" void kernel_launch(void* const* d_in, const int* in_sizes, int n_in,
                              void* d_out, int out_size, void* d_ws, size_t ws_size,
                              hipStream_t stream) {
  const float* xyz = (const float*)d_in[0];
  const float* txy = (const float*)d_in[1];
  const float* tyz = (const float*)d_in[2];
  const float* txz = (const float*)d_in[3];
  const int* step  = (const int*)d_in[4];
  float* out = (float*)d_out;
  const int n = in_sizes[0] / 3;

  // Replicate _meta() in double precision (margins >= 0.0128 to every ceil
  // boundary -- far beyond any libm 1-ulp difference vs numpy).
  Meta meta;
  unsigned off = 0;
  const double pls = std::exp2(std::log2(2048.0 / 16.0) / 15.0);
  for (int l = 0; l < 16; ++l) {
    const double scale = 16.0 * std::pow(pls, (double)l) - 1.0;
    const unsigned res = (unsigned)std::ceil(scale) + 1u;
    unsigned long long params = (unsigned long long)res * (unsigned long long)res;
    if (params > (1ull << 19)) params = (1ull << 19);
    params = ((params + 7ull) / 8ull) * 8ull;
    if (l < kLevels) {
      meta.lv[l].scale = (float)scale;
      meta.lv[l].res = res;
      meta.lv[l].size = (unsigned)params;
      meta.lv[l].off = off;
    }
    off += (unsigned)params;
  }

  const dim3 block(256);
  const dim3 grid((unsigned)((n + 255) / 256));

  const size_t sorted_off = 256 * 1024;
  const size_t need = sorted_off + (size_t)n * sizeof(f32x4);

  if (ws_size >= need) {
    unsigned* counts = (unsigned*)d_ws;
    unsigned* cursor = counts + kNB;
    f32x4* sorted = (f32x4*)((char*)d_ws + sorted_off);

    hipMemsetAsync(counts, 0, kNB * sizeof(unsigned), stream);
    hipLaunchKernelGGL(k_hist, grid, block, 0, stream, xyz, counts, n);
    hipLaunchKernelGGL(k_scan, dim3(1), dim3(1024), 0, stream, counts, cursor);
    hipLaunchKernelGGL(k_scatter, grid, block, 0, stream, xyz, cursor, sorted, n);
    hipLaunchKernelGGL(k_main_sorted, grid, block, 0, stream,
                       sorted, txy, tyz, txz, step, out, n, meta);
  } else {
    hipLaunchKernelGGL(k_fused_linear, grid, block, 0, stream,
                       xyz, txy, tyz, txz, step, out, n, meta);
  }
}